// Round 3
// baseline (290.881 us; speedup 1.0000x reference)
//
#include <hip/hip_runtime.h>
#include <hip/hip_bf16.h>

typedef __attribute__((ext_vector_type(8))) short bf16x8;
typedef __attribute__((ext_vector_type(4))) float f32x4;

// Problem constants
#define SPLITN 32
#define DDIM   256
#define UNITS  256
#define BROWS  4096

// GEMM tile config: one block = 64 rows x all 256 units, K-steps of 32
#define BM 64
#define BN 256
#define BK 32
#define NKT (DDIM / BK)   // 8

static __device__ __forceinline__ ushort f2bf(float f) {
    __hip_bfloat16 h = __float2bfloat16(f);
    return *reinterpret_cast<ushort*>(&h);
}

// XOR swizzle for [row][32] bf16 tiles (64 B rows): rows r, r+8 alias -> 2-way (free).
static __device__ __forceinline__ int swz(int row, int e) {
    return (row * BK + e) ^ (((row >> 1) & 3) << 3);
}

// ---------------------------------------------------------------------------
// Prep: W[s][d][u] fp32  ->  Wt[s][u][d] bf16   (LDS-tiled transpose+convert)
// grid (4,4,32) x 256 threads, 64x64 tiles
// ---------------------------------------------------------------------------
__global__ __launch_bounds__(256) void wt_prep(const float* __restrict__ W,
                                               ushort* __restrict__ Wt) {
    __shared__ float tile[64][65];   // +1 pad: conflict-free transpose
    const int s  = blockIdx.z;
    const int d0 = blockIdx.y * 64;
    const int u0 = blockIdx.x * 64;
    const int t  = threadIdx.x;

    const float* Ws = W + s * 65536;
    #pragma unroll
    for (int i = 0; i < 4; ++i) {
        int f  = t + i * 256;        // 1024 float4 chunks
        int d  = f >> 4;             // 16 float4 per 64-wide row
        int uq = f & 15;
        f32x4 v = *reinterpret_cast<const f32x4*>(Ws + (d0 + d) * 256 + u0 + uq * 4);
        tile[d][uq * 4 + 0] = v[0];
        tile[d][uq * 4 + 1] = v[1];
        tile[d][uq * 4 + 2] = v[2];
        tile[d][uq * 4 + 3] = v[3];
    }
    __syncthreads();

    ushort* Wts = Wt + s * 65536;
    #pragma unroll
    for (int i = 0; i < 4; ++i) {
        int g  = t + i * 256;
        int u  = g >> 4;
        int dq = g & 15;
        uint lo = (uint)f2bf(tile[dq * 4 + 0][u]) | ((uint)f2bf(tile[dq * 4 + 1][u]) << 16);
        uint hi = (uint)f2bf(tile[dq * 4 + 2][u]) | ((uint)f2bf(tile[dq * 4 + 3][u]) << 16);
        uint2 val; val.x = lo; val.y = hi;
        *reinterpret_cast<uint2*>(Wts + (u0 + u) * 256 + d0 + dq * 4) = val;
    }
}

// ---------------------------------------------------------------------------
// Main GEMM: per split s, out[:, s, :] = relu(x[:, s, :] @ W_s + b_s)
// 2048 blocks (XCD-swizzled), 256 threads = 4 waves (1x4 along N).
// 64x256 tile, BK=32, double-buffered LDS, 2-phase prefetch:
//   issue loads(t+1) -> ds_read+MFMA(t) -> convert+ds_write(t+1) -> barrier
// ---------------------------------------------------------------------------
__global__ __launch_bounds__(256, 3) void lc_gemm(const float* __restrict__ x,
                                                  const ushort* __restrict__ Wt,
                                                  const float* __restrict__ bias,
                                                  float* __restrict__ out) {
    // bijective XCD swizzle: 2048 % 8 == 0
    const int bid = blockIdx.x;
    const int sw  = (bid & 7) * 256 + (bid >> 3);
    const int s   = sw >> 6;           // 32 splits, 64 blocks each
    const int mt  = sw & 63;           // 64 M-tiles of 64 rows
    const int m0  = mt * BM;

    __shared__ ushort As[2][BM * BK];  // 2 x 4 KiB
    __shared__ ushort Bs[2][BN * BK];  // 2 x 16 KiB

    const int t  = threadIdx.x;
    const int wc = t >> 6;             // wave -> 64-col slice
    const int l  = t & 63;
    const int lr = l & 15, lg = l >> 4;

    // staging decomposition (per iter):
    //   A: 512 f32x4 chunks, 2/thread:  m = f>>3 (8 chunks/row), kq = f&7
    //   B: 1024 int4 chunks, 4/thread:  u = f>>2 (4 chunks/row), dq = f&3
    const int am0 = t >> 3,  akq = t & 7;     // + i*32 rows
    const int bu0 = t >> 2,  bdq = t & 3;     // + i*64 rows

    const float*  xA = x  + (long)m0 * 8192 + s * 256;   // x[m0+m][s][*]
    const ushort* WB = Wt + s * 65536;                   // Wt[s][u][*]

    f32x4 acc[4][4];
    #pragma unroll
    for (int i = 0; i < 4; ++i)
        #pragma unroll
        for (int j = 0; j < 4; ++j) {
            f32x4 z = {0.f, 0.f, 0.f, 0.f};
            acc[i][j] = z;
        }

    // ---- prologue: stage tile 0 into buffer 0 ----
    {
        f32x4 av0 = *reinterpret_cast<const f32x4*>(xA + am0 * 8192 + akq * 4);
        f32x4 av1 = *reinterpret_cast<const f32x4*>(xA + (am0 + 32) * 8192 + akq * 4);
        int4  bv0 = *reinterpret_cast<const int4*>(WB + bu0 * 256 + bdq * 8);
        int4  bv1 = *reinterpret_cast<const int4*>(WB + (bu0 + 64) * 256 + bdq * 8);
        int4  bv2 = *reinterpret_cast<const int4*>(WB + (bu0 + 128) * 256 + bdq * 8);
        int4  bv3 = *reinterpret_cast<const int4*>(WB + (bu0 + 192) * 256 + bdq * 8);
        uint2 w0, w1;
        w0.x = (uint)f2bf(av0[0]) | ((uint)f2bf(av0[1]) << 16);
        w0.y = (uint)f2bf(av0[2]) | ((uint)f2bf(av0[3]) << 16);
        w1.x = (uint)f2bf(av1[0]) | ((uint)f2bf(av1[1]) << 16);
        w1.y = (uint)f2bf(av1[2]) | ((uint)f2bf(av1[3]) << 16);
        *reinterpret_cast<uint2*>(&As[0][swz(am0,      akq * 4)]) = w0;
        *reinterpret_cast<uint2*>(&As[0][swz(am0 + 32, akq * 4)]) = w1;
        *reinterpret_cast<int4*>(&Bs[0][swz(bu0,       bdq * 8)]) = bv0;
        *reinterpret_cast<int4*>(&Bs[0][swz(bu0 + 64,  bdq * 8)]) = bv1;
        *reinterpret_cast<int4*>(&Bs[0][swz(bu0 + 128, bdq * 8)]) = bv2;
        *reinterpret_cast<int4*>(&Bs[0][swz(bu0 + 192, bdq * 8)]) = bv3;
    }
    __syncthreads();

    // ---- main loop: 8 K-steps, fully unrolled (static buffer indices) ----
    #pragma unroll
    for (int kt = 0; kt < NKT; ++kt) {
        const int cur = kt & 1, nxt = cur ^ 1;

        // phase 1: issue next tile's global loads (in flight across MFMA)
        f32x4 av0, av1; int4 bv0, bv1, bv2, bv3;
        if (kt < NKT - 1) {
            const int k0 = (kt + 1) * BK;
            av0 = *reinterpret_cast<const f32x4*>(xA + am0 * 8192 + k0 + akq * 4);
            av1 = *reinterpret_cast<const f32x4*>(xA + (am0 + 32) * 8192 + k0 + akq * 4);
            bv0 = *reinterpret_cast<const int4*>(WB + bu0 * 256 + k0 + bdq * 8);
            bv1 = *reinterpret_cast<const int4*>(WB + (bu0 + 64) * 256 + k0 + bdq * 8);
            bv2 = *reinterpret_cast<const int4*>(WB + (bu0 + 128) * 256 + k0 + bdq * 8);
            bv3 = *reinterpret_cast<const int4*>(WB + (bu0 + 192) * 256 + k0 + bdq * 8);
        }

        // phase 2: compute current tile
        bf16x8 af[4], bf[4];
        #pragma unroll
        for (int mi = 0; mi < 4; ++mi) {
            int row = mi * 16 + lr;
            af[mi] = *reinterpret_cast<const bf16x8*>(&As[cur][swz(row, lg * 8)]);
        }
        #pragma unroll
        for (int ni = 0; ni < 4; ++ni) {
            int row = wc * 64 + ni * 16 + lr;
            bf[ni] = *reinterpret_cast<const bf16x8*>(&Bs[cur][swz(row, lg * 8)]);
        }
        #pragma unroll
        for (int mi = 0; mi < 4; ++mi)
            #pragma unroll
            for (int ni = 0; ni < 4; ++ni)
                acc[mi][ni] = __builtin_amdgcn_mfma_f32_16x16x32_bf16(
                    af[mi], bf[ni], acc[mi][ni], 0, 0, 0);

        // phase 3: convert + write next tile into the other buffer
        if (kt < NKT - 1) {
            uint2 w0, w1;
            w0.x = (uint)f2bf(av0[0]) | ((uint)f2bf(av0[1]) << 16);
            w0.y = (uint)f2bf(av0[2]) | ((uint)f2bf(av0[3]) << 16);
            w1.x = (uint)f2bf(av1[0]) | ((uint)f2bf(av1[1]) << 16);
            w1.y = (uint)f2bf(av1[2]) | ((uint)f2bf(av1[3]) << 16);
            *reinterpret_cast<uint2*>(&As[nxt][swz(am0,      akq * 4)]) = w0;
            *reinterpret_cast<uint2*>(&As[nxt][swz(am0 + 32, akq * 4)]) = w1;
            *reinterpret_cast<int4*>(&Bs[nxt][swz(bu0,       bdq * 8)]) = bv0;
            *reinterpret_cast<int4*>(&Bs[nxt][swz(bu0 + 64,  bdq * 8)]) = bv1;
            *reinterpret_cast<int4*>(&Bs[nxt][swz(bu0 + 128, bdq * 8)]) = bv2;
            *reinterpret_cast<int4*>(&Bs[nxt][swz(bu0 + 192, bdq * 8)]) = bv3;
            __syncthreads();
        }
    }

    // ---- epilogue: bias + relu, fp32 stores ----
    // C/D layout (verified m89/m91): col = lane&15, row = (lane>>4)*4 + reg
    #pragma unroll
    for (int ni = 0; ni < 4; ++ni) {
        int col = wc * 64 + ni * 16 + lr;
        float bv = bias[s * 256 + col];
        #pragma unroll
        for (int mi = 0; mi < 4; ++mi) {
            int row0 = m0 + mi * 16 + lg * 4;
            #pragma unroll
            for (int rr = 0; rr < 4; ++rr) {
                float v = acc[mi][ni][rr] + bv;
                out[(long)(row0 + rr) * 8192 + s * 256 + col] = fmaxf(v, 0.f);
            }
        }
    }
}

// ---------------------------------------------------------------------------
// Fallback (only if workspace is too small for Wt): naive fp32 dot per output
// ---------------------------------------------------------------------------
__global__ void naive_lc(const float* __restrict__ x, const float* __restrict__ W,
                         const float* __restrict__ b, float* __restrict__ out,
                         int total) {
    int i = blockIdx.x * blockDim.x + threadIdx.x;
    if (i >= total) return;
    int u = i & 255;
    int s = (i >> 8) & 31;
    int bi = i >> 13;
    const float* xr = x + (long)bi * 8192 + s * 256;
    const float* wc = W + s * 65536 + u;
    float acc = 0.f;
    #pragma unroll 4
    for (int d = 0; d < 256; ++d) acc += xr[d] * wc[d * 256];
    out[i] = fmaxf(acc + b[s * 256 + u], 0.f);
}

extern "C" void kernel_launch(void* const* d_in, const int* in_sizes, int n_in,
                              void* d_out, int out_size, void* d_ws, size_t ws_size,
                              hipStream_t stream) {
    const float* x = (const float*)d_in[0];
    const float* W = (const float*)d_in[1];
    const float* b = (const float*)d_in[2];
    float* out = (float*)d_out;

    const size_t wt_bytes = (size_t)SPLITN * DDIM * UNITS * sizeof(ushort); // 4 MiB
    if (ws_size >= wt_bytes) {
        ushort* Wt = (ushort*)d_ws;
        wt_prep<<<dim3(4, 4, 32), 256, 0, stream>>>(W, Wt);
        lc_gemm<<<dim3(2048), 256, 0, stream>>>(x, Wt, b, out);
    } else {
        int total = BROWS * SPLITN * UNITS;
        naive_lc<<<(total + 255) / 256, 256, 0, stream>>>(x, W, b, out, total);
    }
}

// Round 4
// 270.068 us; speedup vs baseline: 1.0771x; 1.0771x over previous
//
#include <hip/hip_runtime.h>
#include <hip/hip_bf16.h>

typedef __attribute__((ext_vector_type(8))) short bf16x8;
typedef __attribute__((ext_vector_type(4))) float f32x4;

// Problem constants
#define SPLITN 32
#define DDIM   256
#define UNITS  256
#define BROWS  4096

#define NIT  16                 // M-iters per block, 16 rows each => 256 rows/block
#define MCHN (BROWS / (NIT * 16))  // 16 M-chunks

static __device__ __forceinline__ ushort f2bf(float f) {
    __hip_bfloat16 h = __float2bfloat16(f);
    return *reinterpret_cast<ushort*>(&h);
}

static __device__ __forceinline__ bf16x8 cvt8(f32x4 lo, f32x4 hi) {
    union { uint u32[4]; bf16x8 v; } r;
    r.u32[0] = (uint)f2bf(lo[0]) | ((uint)f2bf(lo[1]) << 16);
    r.u32[1] = (uint)f2bf(lo[2]) | ((uint)f2bf(lo[3]) << 16);
    r.u32[2] = (uint)f2bf(hi[0]) | ((uint)f2bf(hi[1]) << 16);
    r.u32[3] = (uint)f2bf(hi[2]) | ((uint)f2bf(hi[3]) << 16);
    return r.v;
}

// ---------------------------------------------------------------------------
// Prep: W[s][d][u] fp32  ->  Wt[s][u][d] bf16   (LDS-tiled transpose+convert)
// grid (4,4,32) x 256 threads, 64x64 tiles
// ---------------------------------------------------------------------------
__global__ __launch_bounds__(256) void wt_prep(const float* __restrict__ W,
                                               ushort* __restrict__ Wt) {
    __shared__ float tile[64][65];   // +1 pad: conflict-free transpose
    const int s  = blockIdx.z;
    const int d0 = blockIdx.y * 64;
    const int u0 = blockIdx.x * 64;
    const int t  = threadIdx.x;

    const float* Ws = W + s * 65536;
    #pragma unroll
    for (int i = 0; i < 4; ++i) {
        int f  = t + i * 256;        // 1024 float4 chunks
        int d  = f >> 4;             // 16 float4 per 64-wide row
        int uq = f & 15;
        f32x4 v = *reinterpret_cast<const f32x4*>(Ws + (d0 + d) * 256 + u0 + uq * 4);
        tile[d][uq * 4 + 0] = v[0];
        tile[d][uq * 4 + 1] = v[1];
        tile[d][uq * 4 + 2] = v[2];
        tile[d][uq * 4 + 3] = v[3];
    }
    __syncthreads();

    ushort* Wts = Wt + s * 65536;
    #pragma unroll
    for (int i = 0; i < 4; ++i) {
        int g  = t + i * 256;
        int u  = g >> 4;
        int dq = g & 15;
        uint lo = (uint)f2bf(tile[dq * 4 + 0][u]) | ((uint)f2bf(tile[dq * 4 + 1][u]) << 16);
        uint hi = (uint)f2bf(tile[dq * 4 + 2][u]) | ((uint)f2bf(tile[dq * 4 + 3][u]) << 16);
        uint2 val; val.x = lo; val.y = hi;
        *reinterpret_cast<uint2*>(Wts + (u0 + u) * 256 + d0 + dq * 4) = val;
    }
}

// ---------------------------------------------------------------------------
// Persistent-B streaming GEMM: NO LDS, NO barriers.
// Grid 512 blocks (32 splits x 16 M-chunks), 256 threads = 4 waves.
// Each wave: holds its 64-col x 256-K B-slice in 128 VGPRs (loaded once),
// then streams 16 iters of 16 rows: A global->reg->bf16->MFMA, NT stores.
// Loads for iter t+1 are issued interleaved with iter t's MFMAs (per-chunk),
// giving each load a full loop body (~300+ cyc) to return; compiler emits
// counted vmcnt, never 0; no barrier drains anywhere.
// ---------------------------------------------------------------------------
__global__ __launch_bounds__(256, 2) void lc_gemm(const float* __restrict__ x,
                                                  const ushort* __restrict__ Wt,
                                                  const float* __restrict__ bias,
                                                  float* __restrict__ out) {
    // bijective XCD swizzle: 512 % 8 == 0
    const int bid = blockIdx.x;
    const int sw  = (bid & 7) * 64 + (bid >> 3);
    const int s   = sw >> 4;            // split
    const int mc  = sw & 15;            // M-chunk
    const int m0  = mc * (NIT * 16);

    const int t  = threadIdx.x;
    const int wc = t >> 6;              // wave -> 64-col slice
    const int l  = t & 63;
    const int lr = l & 15;              // fragment row/col within 16
    const int lg = l >> 4;              // k-subgroup (x8 elements)

    // ---- B: whole 64x256 wave-slice in registers: Bf[ni][k], 128 VGPRs ----
    bf16x8 Bf[4][8];
    {
        const ushort* wb = Wt + s * 65536 + (wc * 64 + lr) * 256 + lg * 8;
        #pragma unroll
        for (int ni = 0; ni < 4; ++ni)
            #pragma unroll
            for (int k = 0; k < 8; ++k)
                Bf[ni][k] = *reinterpret_cast<const bf16x8*>(wb + ni * (16 * 256) + k * 32);
    }

    float bv[4];
    #pragma unroll
    for (int ni = 0; ni < 4; ++ni)
        bv[ni] = bias[s * 256 + wc * 64 + ni * 16 + lr];

    // per-lane A pointer: row m0+lr, k-offset lg*8 (A-frag: row=l&15, k=(l>>4)*8+j)
    const float* xp = x + (long)(m0 + lr) * 8192 + s * 256 + lg * 8;

    // ---- prologue: load iter-0 A (16 rows x 256 K, 32B per lane per chunk) ----
    f32x4 a[8][2];
    #pragma unroll
    for (int k = 0; k < 8; ++k) {
        a[k][0] = *reinterpret_cast<const f32x4*>(xp + k * 32);
        a[k][1] = *reinterpret_cast<const f32x4*>(xp + k * 32 + 4);
    }

    // out base: row m0 + lg*4, col wc*64 + lr  (C/D: row=(l>>4)*4+rr, col=l&15)
    float* op = out + (long)(m0 + lg * 4) * 8192 + s * 256 + wc * 64 + lr;

    for (int it = 0; it < NIT; ++it) {
        // next iter's row base (clamped on last iter; loads harmless/unused)
        const int nit = (it + 1 < NIT) ? (it + 1) : it;
        const float* xn = xp + (long)nit * (16 * 8192);

        f32x4 acc[4];
        #pragma unroll
        for (int ni = 0; ni < 4; ++ni) {
            f32x4 z = {0.f, 0.f, 0.f, 0.f};
            acc[ni] = z;
        }

        #pragma unroll
        for (int k = 0; k < 8; ++k) {
            // convert current chunk (frees a[k] for the prefetch below)
            bf16x8 af = cvt8(a[k][0], a[k][1]);
            // issue next-iter chunk-k loads (consumed one full body later)
            f32x4 n0 = *reinterpret_cast<const f32x4*>(xn + k * 32);
            f32x4 n1 = *reinterpret_cast<const f32x4*>(xn + k * 32 + 4);
            #pragma unroll
            for (int ni = 0; ni < 4; ++ni)
                acc[ni] = __builtin_amdgcn_mfma_f32_16x16x32_bf16(
                    af, Bf[ni][k], acc[ni], 0, 0, 0);
            a[k][0] = n0;
            a[k][1] = n1;
        }

        // epilogue for these 16 rows: bias + relu, nontemporal dword stores
        #pragma unroll
        for (int ni = 0; ni < 4; ++ni) {
            #pragma unroll
            for (int rr = 0; rr < 4; ++rr) {
                float v = fmaxf(acc[ni][rr] + bv[ni], 0.f);
                __builtin_nontemporal_store(
                    v, op + (long)(it * 16 + rr) * 8192 + ni * 16);
            }
        }
    }
}

// ---------------------------------------------------------------------------
// Fallback (only if workspace is too small for Wt): naive fp32 dot per output
// ---------------------------------------------------------------------------
__global__ void naive_lc(const float* __restrict__ x, const float* __restrict__ W,
                         const float* __restrict__ b, float* __restrict__ out,
                         int total) {
    int i = blockIdx.x * blockDim.x + threadIdx.x;
    if (i >= total) return;
    int u = i & 255;
    int s = (i >> 8) & 31;
    int bi = i >> 13;
    const float* xr = x + (long)bi * 8192 + s * 256;
    const float* wc = W + s * 65536 + u;
    float acc = 0.f;
    #pragma unroll 4
    for (int d = 0; d < 256; ++d) acc += xr[d] * wc[d * 256];
    out[i] = fmaxf(acc + b[s * 256 + u], 0.f);
}

extern "C" void kernel_launch(void* const* d_in, const int* in_sizes, int n_in,
                              void* d_out, int out_size, void* d_ws, size_t ws_size,
                              hipStream_t stream) {
    const float* x = (const float*)d_in[0];
    const float* W = (const float*)d_in[1];
    const float* b = (const float*)d_in[2];
    float* out = (float*)d_out;

    const size_t wt_bytes = (size_t)SPLITN * DDIM * UNITS * sizeof(ushort); // 4 MiB
    if (ws_size >= wt_bytes) {
        ushort* Wt = (ushort*)d_ws;
        wt_prep<<<dim3(4, 4, 32), 256, 0, stream>>>(W, Wt);
        lc_gemm<<<dim3(SPLITN * MCHN), 256, 0, stream>>>(x, Wt, b, out);
    } else {
        int total = BROWS * SPLITN * UNITS;
        naive_lc<<<(total + 255) / 256, 256, 0, stream>>>(x, W, b, out, total);
    }
}